// Round 1
// baseline (751.525 us; speedup 1.0000x reference)
//
#include <hip/hip_runtime.h>
#include <math.h>

// ---------------- degree / dinv ----------------

__global__ __launch_bounds__(256) void k_deg(const int* __restrict__ dst, int* __restrict__ deg, int E) {
  int e = blockIdx.x * 256 + threadIdx.x;
  if (e < E) atomicAdd(&deg[dst[e]], 1);
}

__global__ __launch_bounds__(256) void k_dinv(const int* __restrict__ deg, float* __restrict__ dinv, int N) {
  int i = blockIdx.x * 256 + threadIdx.x;
  if (i < N) dinv[i] = rsqrtf((float)(deg[i] + 1));  // +1 = self loop
}

// ---------------- exclusive scan (3 kernels, 1024 elems/block) ----------------

__global__ __launch_bounds__(256) void k_scan1(const int* __restrict__ deg, int* __restrict__ bsum, int N) {
  __shared__ int sm[256];
  int tid = threadIdx.x;
  int base = blockIdx.x * 1024 + tid * 4;
  int s = 0;
#pragma unroll
  for (int j = 0; j < 4; ++j) { int i = base + j; if (i < N) s += deg[i]; }
  sm[tid] = s; __syncthreads();
  for (int st = 128; st > 0; st >>= 1) { if (tid < st) sm[tid] += sm[tid + st]; __syncthreads(); }
  if (tid == 0) bsum[blockIdx.x] = sm[0];
}

// single wave scans up to 128 block sums
__global__ __launch_bounds__(64) void k_scan2(const int* __restrict__ bsum, int* __restrict__ boff, int nb) {
  int lane = threadIdx.x;
  int v0 = (lane < nb) ? bsum[lane] : 0;
  int v1 = (lane + 64 < nb) ? bsum[lane + 64] : 0;
  int s0 = v0;
#pragma unroll
  for (int st = 1; st < 64; st <<= 1) { int t = __shfl_up(s0, st); if (lane >= st) s0 += t; }
  int tot0 = __shfl(s0, 63);
  int s1 = v1;
#pragma unroll
  for (int st = 1; st < 64; st <<= 1) { int t = __shfl_up(s1, st); if (lane >= st) s1 += t; }
  s1 += tot0;
  if (lane < nb) boff[lane] = s0 - v0;
  if (lane + 64 < nb) boff[lane + 64] = s1 - v1;
}

__global__ __launch_bounds__(256) void k_scan3(const int* __restrict__ deg, const int* __restrict__ boff,
                                               int* __restrict__ rowptr, int* __restrict__ cursor,
                                               int N, int E) {
  __shared__ int sm[256];
  int tid = threadIdx.x;
  int base = blockIdx.x * 1024 + tid * 4;
  int v[4]; int s = 0;
#pragma unroll
  for (int j = 0; j < 4; ++j) { int i = base + j; v[j] = (i < N) ? deg[i] : 0; s += v[j]; }
  sm[tid] = s; __syncthreads();
  for (int st = 1; st < 256; st <<= 1) {
    int t = 0;
    if (tid >= st) t = sm[tid - st];
    __syncthreads();
    sm[tid] += t;
    __syncthreads();
  }
  int excl = sm[tid] - s + boff[blockIdx.x];
  int run = excl;
#pragma unroll
  for (int j = 0; j < 4; ++j) {
    int i = base + j;
    if (i < N) { rowptr[i] = run; cursor[i] = run; }
    run += v[j];
  }
  if (blockIdx.x == 0 && tid == 0) rowptr[N] = E;
}

__global__ __launch_bounds__(256) void k_scatter(const int* __restrict__ src, const int* __restrict__ dst,
                                                 int* __restrict__ cursor, int* __restrict__ csr, int E) {
  int e = blockIdx.x * 256 + threadIdx.x;
  if (e < E) {
    int pos = atomicAdd(&cursor[dst[e]], 1);
    csr[pos] = src[e];
  }
}

// ---------------- GEMM + dinv prescale: g = dinv * (x @ W) ----------------
// Each thread: ROWS nodes x VPT features. W and x tile staged in LDS.
// x tile XOR-swizzled (row&31) so simultaneous broadcast reads of different
// rows hit different banks.

template <int F_IN, int F_OUT, int TPN, int ROWS>
__global__ __launch_bounds__(256) void k_gemm(const float* __restrict__ x, const float* __restrict__ W,
                                              const float* __restrict__ dinv, float* __restrict__ g, int N) {
  constexpr int VPT = F_OUT / TPN;
  constexpr int GROUPS = 256 / TPN;
  constexpr int NB = GROUPS * ROWS;
  __shared__ float ws[F_IN * F_OUT];
  __shared__ float xs[NB][F_IN];
  int tid = threadIdx.x;
  int base = blockIdx.x * NB;
  for (int i = tid; i < F_IN * F_OUT; i += 256) ws[i] = W[i];
  for (int i = tid; i < NB * F_IN; i += 256) {
    int r = i / F_IN, c = i - r * F_IN;
    int node = base + r;
    xs[r][c ^ (r & 31)] = (node < N) ? x[(size_t)node * F_IN + c] : 0.f;
  }
  __syncthreads();
  int fg = tid % TPN, f0 = fg * VPT;
  int ng = tid / TPN;
  int r0 = ng * ROWS;
  float acc[ROWS][VPT];
#pragma unroll
  for (int r = 0; r < ROWS; ++r)
#pragma unroll
    for (int j = 0; j < VPT; ++j) acc[r][j] = 0.f;
  for (int k = 0; k < F_IN; ++k) {
    float wv[VPT];
#pragma unroll
    for (int j = 0; j < VPT; ++j) wv[j] = ws[k * F_OUT + f0 + j];
#pragma unroll
    for (int r = 0; r < ROWS; ++r) {
      float xv = xs[r0 + r][k ^ ((r0 + r) & 31)];
#pragma unroll
      for (int j = 0; j < VPT; ++j) acc[r][j] += xv * wv[j];
    }
  }
#pragma unroll
  for (int r = 0; r < ROWS; ++r) {
    int node = base + r0 + r;
    if (node < N) {
      float dv = dinv[node];
#pragma unroll
      for (int j = 0; j < VPT; ++j) g[(size_t)node * F_OUT + f0 + j] = dv * acc[r][j];
    }
  }
}

// ---------------- CSR aggregation: out = maybe_relu(dinv*(self + sum_in) + b) ----------------
// F lanes per node, lane = feature. Edge-id loads 4-wide (aligned), each lane
// reads g row slice (coalesced 4B*F).

template <int F, bool RELU>
__global__ __launch_bounds__(256) void k_agg(const float* __restrict__ g, const int* __restrict__ rowptr,
                                             const int* __restrict__ csr, const float* __restrict__ dinv,
                                             const float* __restrict__ bias, float* __restrict__ out, int N) {
  int t = blockIdx.x * 256 + threadIdx.x;
  int grp = t / F;
  int f = t - grp * F;
  if (grp >= N) return;
  float acc = g[(size_t)grp * F + f];  // self loop term
  int beg = rowptr[grp], end = rowptr[grp + 1];
  int j = beg;
  while (j < end && (j & 3)) { acc += g[(size_t)csr[j] * F + f]; ++j; }
  for (; j + 4 <= end; j += 4) {
    int4 ss = *(const int4*)(csr + j);
    float a0 = g[(size_t)ss.x * F + f];
    float a1 = g[(size_t)ss.y * F + f];
    float a2 = g[(size_t)ss.z * F + f];
    float a3 = g[(size_t)ss.w * F + f];
    acc += a0; acc += a1; acc += a2; acc += a3;
  }
  for (; j < end; ++j) acc += g[(size_t)csr[j] * F + f];
  float v = dinv[grp] * acc + bias[f];
  if (RELU) v = fmaxf(v, 0.f);
  out[(size_t)grp * F + f] = v;
}

// ---------------- final layer aggregation (F=2) + log_softmax ----------------

__global__ __launch_bounds__(256) void k_final(const float* __restrict__ g, const int* __restrict__ rowptr,
                                               const int* __restrict__ csr, const float* __restrict__ dinv,
                                               const float* __restrict__ bias, float* __restrict__ out, int N) {
  int i = blockIdx.x * 256 + threadIdx.x;
  if (i >= N) return;
  float a0 = g[2 * (size_t)i], a1 = g[2 * (size_t)i + 1];
  int beg = rowptr[i], end = rowptr[i + 1];
  for (int j = beg; j < end; ++j) {
    int s = csr[j];
    a0 += g[2 * (size_t)s];
    a1 += g[2 * (size_t)s + 1];
  }
  float dv = dinv[i];
  float v0 = fmaf(dv, a0, bias[0]);
  float v1 = fmaf(dv, a1, bias[1]);
  float m = fmaxf(v0, v1);
  float lse = m + logf(expf(v0 - m) + expf(v1 - m));
  out[2 * (size_t)i] = v0 - lse;
  out[2 * (size_t)i + 1] = v1 - lse;
}

// ---------------- launch ----------------

extern "C" void kernel_launch(void* const* d_in, const int* in_sizes, int n_in,
                              void* d_out, int out_size, void* d_ws, size_t ws_size,
                              hipStream_t stream) {
  const float* x  = (const float*)d_in[0];
  const int*   ei = (const int*)d_in[1];
  const float* W1 = (const float*)d_in[2];
  const float* b1 = (const float*)d_in[3];
  const float* W2 = (const float*)d_in[4];
  const float* b2 = (const float*)d_in[5];
  const float* W3 = (const float*)d_in[6];
  const float* b3 = (const float*)d_in[7];
  float* out = (float*)d_out;

  int N = in_sizes[0] / 128;  // 100000
  int E = in_sizes[1] / 2;    // 3200000
  const int* src = ei;        // edge_index[0]
  const int* dst = ei + E;    // edge_index[1]

  char* w = (char*)d_ws;
  size_t off = 0;
  auto carve = [&](size_t bytes) -> char* {
    char* p = w + off;
    off = (off + bytes + 255) & ~(size_t)255;
    return p;
  };
  int*   deg    = (int*)carve((size_t)N * 4);
  float* dinv   = (float*)carve((size_t)N * 4);
  int*   rowptr = (int*)carve((size_t)(N + 1) * 4);
  int*   cursor = (int*)carve((size_t)N * 4);
  int*   bsum   = (int*)carve(512);
  int*   boff   = (int*)carve(512);
  int*   csr    = (int*)carve((size_t)E * 4);
  float* gbuf   = (float*)carve((size_t)N * 64 * 4);
  float* hbuf   = (float*)carve((size_t)N * 64 * 4);
  (void)ws_size; (void)n_in; (void)out_size;

  hipMemsetAsync(deg, 0, (size_t)N * 4, stream);
  k_deg<<<(E + 255) / 256, 256, 0, stream>>>(dst, deg, E);
  k_dinv<<<(N + 255) / 256, 256, 0, stream>>>(deg, dinv, N);

  int nb = (N + 1023) / 1024;  // 98 <= 128
  k_scan1<<<nb, 256, 0, stream>>>(deg, bsum, N);
  k_scan2<<<1, 64, 0, stream>>>(bsum, boff, nb);
  k_scan3<<<nb, 256, 0, stream>>>(deg, boff, rowptr, cursor, N, E);
  k_scatter<<<(E + 255) / 256, 256, 0, stream>>>(src, dst, cursor, csr, E);

  // layer 1: 128 -> 64, relu
  k_gemm<128, 64, 16, 4><<<(N + 63) / 64, 256, 0, stream>>>(x, W1, dinv, gbuf, N);
  k_agg<64, true><<<(unsigned)(((long long)N * 64 + 255) / 256), 256, 0, stream>>>(gbuf, rowptr, csr, dinv, b1, hbuf, N);
  // layer 2: 64 -> 32, relu
  k_gemm<64, 32, 8, 4><<<(N + 127) / 128, 256, 0, stream>>>(hbuf, W2, dinv, gbuf, N);
  k_agg<32, true><<<(unsigned)(((long long)N * 32 + 255) / 256), 256, 0, stream>>>(gbuf, rowptr, csr, dinv, b2, hbuf, N);
  // layer 3: 32 -> 2, log_softmax
  k_gemm<32, 2, 1, 1><<<(N + 255) / 256, 256, 0, stream>>>(hbuf, W3, dinv, gbuf, N);
  k_final<<<(N + 255) / 256, 256, 0, stream>>>(gbuf, rowptr, csr, dinv, b3, out, N);
}

// Round 2
// 426.443 us; speedup vs baseline: 1.7623x; 1.7623x over previous
//
#include <hip/hip_runtime.h>
#include <math.h>

#define EPB 8192      // edges per block in bucket passes
#define MAXB 16384    // LDS csr staging capacity (bucket avg ~8192, sd ~90)

// ---------------- pass A0: coarse bucket histogram (bucket = dst>>8) ----------------

__global__ __launch_bounds__(256) void k_bhist(const int* __restrict__ dst, int* __restrict__ bhist,
                                               int E, int NBKT) {
  __shared__ int hist[512];
  int tid = threadIdx.x;
  int ebeg = blockIdx.x * EPB;
  int eend = min(E, ebeg + EPB);
  for (int i = tid; i < NBKT; i += 256) hist[i] = 0;
  __syncthreads();
  for (int e = ebeg + tid; e < eend; e += 256) atomicAdd(&hist[dst[e] >> 8], 1);
  __syncthreads();
  for (int i = tid; i < NBKT; i += 256) {
    int c = hist[i];
    if (c) atomicAdd(&bhist[i], c);
  }
}

// ---------------- bucket scan (single block): bbase, gcur, rowptr[N] ----------------

__global__ __launch_bounds__(256) void k_bscan(const int* __restrict__ bhist, int* __restrict__ bbase,
                                               int* __restrict__ gcur, int* __restrict__ rowptr,
                                               int E, int N, int NBKT) {
  __shared__ int a[512], c[512];
  int tid = threadIdx.x;
  int v0 = (tid < NBKT) ? bhist[tid] : 0;
  int v1 = (tid + 256 < NBKT) ? bhist[tid + 256] : 0;
  a[tid] = v0; a[tid + 256] = v1;
  __syncthreads();
  int* pin = a; int* pout = c;
  for (int st = 1; st < 512; st <<= 1) {
    pout[tid]       = pin[tid]       + ((tid >= st)       ? pin[tid - st]       : 0);
    pout[tid + 256] = pin[tid + 256] + ((tid + 256 >= st) ? pin[tid + 256 - st] : 0);
    __syncthreads();
    int* t = pin; pin = pout; pout = t;
  }
  if (tid < NBKT)       { int ex = pin[tid] - v0;             bbase[tid] = ex;       gcur[tid] = ex; }
  if (tid + 256 < NBKT) { int ex = pin[tid + 256] - v1;       bbase[tid + 256] = ex; gcur[tid + 256] = ex; }
  if (tid == 0) { bbase[NBKT] = E; rowptr[N] = E; }
}

// ---------------- pass A: scatter (src,dst) pairs grouped by coarse bucket ----------------
// One global atomic per (block,bucket) reserves a contiguous run; writes are
// ~170B dense runs -> full-line writebacks (kills the 15x write amplification).

__global__ __launch_bounds__(256) void k_bucket_scatter(const int* __restrict__ src, const int* __restrict__ dst,
                                                        int* __restrict__ gcur, uint2* __restrict__ tmp,
                                                        int E, int NBKT) {
  __shared__ int hist[512], base[512];
  int tid = threadIdx.x;
  int ebeg = blockIdx.x * EPB;
  int eend = min(E, ebeg + EPB);
  for (int i = tid; i < NBKT; i += 256) hist[i] = 0;
  __syncthreads();
  for (int e = ebeg + tid; e < eend; e += 256) atomicAdd(&hist[dst[e] >> 8], 1);
  __syncthreads();
  for (int i = tid; i < NBKT; i += 256) {
    int c = hist[i];
    base[i] = c ? atomicAdd(&gcur[i], c) : 0;
    hist[i] = 0;
  }
  __syncthreads();
  for (int e = ebeg + tid; e < eend; e += 256) {
    int d = dst[e];
    int bkt = d >> 8;
    int o = base[bkt] + atomicAdd(&hist[bkt], 1);
    tmp[o] = make_uint2((unsigned)src[e], (unsigned)d);
  }
}

// ---------------- pass B: per-bucket build: rowptr, dinv, csr (all LDS-local) ----------------

__global__ __launch_bounds__(256) void k_bucket_build(const uint2* __restrict__ tmp, const int* __restrict__ bbase,
                                                      int* __restrict__ csr, int* __restrict__ rowptr,
                                                      float* __restrict__ dinv, int N) {
  int b = blockIdx.x;
  int tid = threadIdx.x;
  int node0 = b << 8;
  int nn = min(256, N - node0);
  int beg = bbase[b], end = bbase[b + 1], cnt = end - beg;
  __shared__ int h[256], off[256], cur[256];
  __shared__ int stage[MAXB];
  h[tid] = 0;
  __syncthreads();
  for (int e = beg + tid; e < end; e += 256) atomicAdd(&h[tmp[e].y & 255], 1);
  __syncthreads();
  int deg = h[tid];
  off[tid] = deg;
  __syncthreads();
  for (int st = 1; st < 256; st <<= 1) {
    int t = (tid >= st) ? off[tid - st] : 0;
    __syncthreads();
    off[tid] += t;
    __syncthreads();
  }
  int excl = off[tid] - deg;
  cur[tid] = excl;
  if (tid < nn) {
    rowptr[node0 + tid] = beg + excl;
    dinv[node0 + tid] = rsqrtf((float)(deg + 1));  // +1 = self loop
  }
  __syncthreads();
  if (cnt <= MAXB) {
    for (int e = beg + tid; e < end; e += 256) {
      uint2 p = tmp[e];
      int pos = atomicAdd(&cur[p.y & 255], 1);
      stage[pos] = (int)p.x;
    }
    __syncthreads();
    for (int k = tid; k < cnt; k += 256) csr[beg + k] = stage[k];
  } else {  // safety fallback (never taken for uniform-random dst)
    for (int e = beg + tid; e < end; e += 256) {
      uint2 p = tmp[e];
      int pos = atomicAdd(&cur[p.y & 255], 1);
      csr[beg + pos] = (int)p.x;
    }
  }
}

// ---------------- GEMM + dinv prescale: g = dinv * (x @ W) ----------------

template <int F_IN, int F_OUT, int TPN, int ROWS>
__global__ __launch_bounds__(256) void k_gemm(const float* __restrict__ x, const float* __restrict__ W,
                                              const float* __restrict__ dinv, float* __restrict__ g, int N) {
  constexpr int VPT = F_OUT / TPN;
  constexpr int GROUPS = 256 / TPN;
  constexpr int NB = GROUPS * ROWS;
  __shared__ float ws[F_IN * F_OUT];
  __shared__ float xs[NB][F_IN];
  int tid = threadIdx.x;
  int base = blockIdx.x * NB;
  for (int i = tid; i < F_IN * F_OUT; i += 256) ws[i] = W[i];
  for (int i = tid; i < NB * F_IN; i += 256) {
    int r = i / F_IN, c = i - r * F_IN;
    int node = base + r;
    xs[r][c ^ (r & 31)] = (node < N) ? x[(size_t)node * F_IN + c] : 0.f;
  }
  __syncthreads();
  int fg = tid % TPN, f0 = fg * VPT;
  int ng = tid / TPN;
  int r0 = ng * ROWS;
  float acc[ROWS][VPT];
#pragma unroll
  for (int r = 0; r < ROWS; ++r)
#pragma unroll
    for (int j = 0; j < VPT; ++j) acc[r][j] = 0.f;
  for (int k = 0; k < F_IN; ++k) {
    float wv[VPT];
#pragma unroll
    for (int j = 0; j < VPT; ++j) wv[j] = ws[k * F_OUT + f0 + j];
#pragma unroll
    for (int r = 0; r < ROWS; ++r) {
      float xv = xs[r0 + r][k ^ ((r0 + r) & 31)];
#pragma unroll
      for (int j = 0; j < VPT; ++j) acc[r][j] += xv * wv[j];
    }
  }
#pragma unroll
  for (int r = 0; r < ROWS; ++r) {
    int node = base + r0 + r;
    if (node < N) {
      float dv = dinv[node];
#pragma unroll
      for (int j = 0; j < VPT; ++j) g[(size_t)node * F_OUT + f0 + j] = dv * acc[r][j];
    }
  }
}

// ---------------- CSR aggregation: out = maybe_relu(dinv*(self + sum_in) + b) ----------------

template <int F, bool RELU>
__global__ __launch_bounds__(256) void k_agg(const float* __restrict__ g, const int* __restrict__ rowptr,
                                             const int* __restrict__ csr, const float* __restrict__ dinv,
                                             const float* __restrict__ bias, float* __restrict__ out, int N) {
  int t = blockIdx.x * 256 + threadIdx.x;
  int grp = t / F;
  int f = t - grp * F;
  if (grp >= N) return;
  float acc = g[(size_t)grp * F + f];  // self loop term
  int beg = rowptr[grp], end = rowptr[grp + 1];
  int j = beg;
  while (j < end && (j & 3)) { acc += g[(size_t)csr[j] * F + f]; ++j; }
  for (; j + 4 <= end; j += 4) {
    int4 ss = *(const int4*)(csr + j);
    float a0 = g[(size_t)ss.x * F + f];
    float a1 = g[(size_t)ss.y * F + f];
    float a2 = g[(size_t)ss.z * F + f];
    float a3 = g[(size_t)ss.w * F + f];
    acc += a0; acc += a1; acc += a2; acc += a3;
  }
  for (; j < end; ++j) acc += g[(size_t)csr[j] * F + f];
  float v = dinv[grp] * acc + bias[f];
  if (RELU) v = fmaxf(v, 0.f);
  out[(size_t)grp * F + f] = v;
}

// ---------------- final layer aggregation (F=2) + log_softmax ----------------

__global__ __launch_bounds__(256) void k_final(const float* __restrict__ g, const int* __restrict__ rowptr,
                                               const int* __restrict__ csr, const float* __restrict__ dinv,
                                               const float* __restrict__ bias, float* __restrict__ out, int N) {
  int i = blockIdx.x * 256 + threadIdx.x;
  if (i >= N) return;
  float a0 = g[2 * (size_t)i], a1 = g[2 * (size_t)i + 1];
  int beg = rowptr[i], end = rowptr[i + 1];
  for (int j = beg; j < end; ++j) {
    int s = csr[j];
    a0 += g[2 * (size_t)s];
    a1 += g[2 * (size_t)s + 1];
  }
  float dv = dinv[i];
  float v0 = fmaf(dv, a0, bias[0]);
  float v1 = fmaf(dv, a1, bias[1]);
  float m = fmaxf(v0, v1);
  float lse = m + logf(expf(v0 - m) + expf(v1 - m));
  out[2 * (size_t)i] = v0 - lse;
  out[2 * (size_t)i + 1] = v1 - lse;
}

// ---------------- launch ----------------

extern "C" void kernel_launch(void* const* d_in, const int* in_sizes, int n_in,
                              void* d_out, int out_size, void* d_ws, size_t ws_size,
                              hipStream_t stream) {
  const float* x  = (const float*)d_in[0];
  const int*   ei = (const int*)d_in[1];
  const float* W1 = (const float*)d_in[2];
  const float* b1 = (const float*)d_in[3];
  const float* W2 = (const float*)d_in[4];
  const float* b2 = (const float*)d_in[5];
  const float* W3 = (const float*)d_in[6];
  const float* b3 = (const float*)d_in[7];
  float* out = (float*)d_out;

  int N = in_sizes[0] / 128;  // 100000
  int E = in_sizes[1] / 2;    // 3200000
  const int* src = ei;        // edge_index[0]
  const int* dst = ei + E;    // edge_index[1]
  int NBKT = (N + 255) >> 8;  // 391 coarse buckets of 256 nodes

  char* w = (char*)d_ws;
  size_t off = 0;
  auto carve = [&](size_t bytes) -> char* {
    char* p = w + off;
    off = (off + bytes + 255) & ~(size_t)255;
    return p;
  };
  float* dinv   = (float*)carve((size_t)N * 4);
  int*   rowptr = (int*)carve((size_t)(N + 1) * 4);
  int*   bhist  = (int*)carve(2048);
  int*   bbase  = (int*)carve(2048 + 4);
  int*   gcur   = (int*)carve(2048);
  int*   csr    = (int*)carve((size_t)E * 4);
  size_t gsz = (size_t)N * 64 * 4;
  if ((size_t)E * 8 > gsz) gsz = (size_t)E * 8;   // gbuf doubles as pair buffer
  float* gbuf   = (float*)carve(gsz);
  float* hbuf   = (float*)carve((size_t)N * 64 * 4);
  uint2* tmp    = (uint2*)gbuf;  // pair buffer dead once k_bucket_build finishes
  (void)ws_size; (void)n_in; (void)out_size;

  int nbA = (E + EPB - 1) / EPB;  // 391

  hipMemsetAsync(bhist, 0, (size_t)NBKT * 4, stream);
  k_bhist<<<nbA, 256, 0, stream>>>(dst, bhist, E, NBKT);
  k_bscan<<<1, 256, 0, stream>>>(bhist, bbase, gcur, rowptr, E, N, NBKT);
  k_bucket_scatter<<<nbA, 256, 0, stream>>>(src, dst, gcur, tmp, E, NBKT);
  k_bucket_build<<<NBKT, 256, 0, stream>>>(tmp, bbase, csr, rowptr, dinv, N);

  // layer 1: 128 -> 64, relu
  k_gemm<128, 64, 16, 4><<<(N + 63) / 64, 256, 0, stream>>>(x, W1, dinv, gbuf, N);
  k_agg<64, true><<<(unsigned)(((long long)N * 64 + 255) / 256), 256, 0, stream>>>(gbuf, rowptr, csr, dinv, b1, hbuf, N);
  // layer 2: 64 -> 32, relu
  k_gemm<64, 32, 8, 4><<<(N + 127) / 128, 256, 0, stream>>>(hbuf, W2, dinv, gbuf, N);
  k_agg<32, true><<<(unsigned)(((long long)N * 32 + 255) / 256), 256, 0, stream>>>(gbuf, rowptr, csr, dinv, b2, hbuf, N);
  // layer 3: 32 -> 2, log_softmax
  k_gemm<32, 2, 1, 1><<<(N + 255) / 256, 256, 0, stream>>>(hbuf, W3, dinv, gbuf, N);
  k_final<<<(N + 255) / 256, 256, 0, stream>>>(gbuf, rowptr, csr, dinv, b3, out, N);
}

// Round 3
// 404.012 us; speedup vs baseline: 1.8602x; 1.0555x over previous
//
#include <hip/hip_runtime.h>
#include <math.h>

#define EPB 8192      // edges per block in bucket passes
#define MAXB 16384    // LDS csr staging capacity (bucket avg ~8192, sd ~90)

// ---------------- bf16 helpers (RNE) ----------------

__device__ inline float b2f(unsigned short u) {
  union { unsigned u32; float f; } c; c.u32 = ((unsigned)u) << 16; return c.f;
}
__device__ inline unsigned short f2b(float f) {
  union { float f; unsigned u; } c; c.f = f;
  unsigned r = c.u + 0x7fff + ((c.u >> 16) & 1);
  return (unsigned short)(r >> 16);
}

// ---------------- pass A0: coarse bucket histogram (bucket = dst>>8) ----------------

__global__ __launch_bounds__(256) void k_bhist(const int* __restrict__ dst, int* __restrict__ bhist,
                                               int E, int NBKT) {
  __shared__ int hist[512];
  int tid = threadIdx.x;
  int ebeg = blockIdx.x * EPB;
  int eend = min(E, ebeg + EPB);
  for (int i = tid; i < NBKT; i += 256) hist[i] = 0;
  __syncthreads();
  for (int e = ebeg + tid; e < eend; e += 256) atomicAdd(&hist[dst[e] >> 8], 1);
  __syncthreads();
  for (int i = tid; i < NBKT; i += 256) {
    int c = hist[i];
    if (c) atomicAdd(&bhist[i], c);
  }
}

// ---------------- bucket scan (single block): bbase, gcur, rowptr[N] ----------------

__global__ __launch_bounds__(256) void k_bscan(const int* __restrict__ bhist, int* __restrict__ bbase,
                                               int* __restrict__ gcur, int* __restrict__ rowptr,
                                               int E, int N, int NBKT) {
  __shared__ int a[512], c[512];
  int tid = threadIdx.x;
  int v0 = (tid < NBKT) ? bhist[tid] : 0;
  int v1 = (tid + 256 < NBKT) ? bhist[tid + 256] : 0;
  a[tid] = v0; a[tid + 256] = v1;
  __syncthreads();
  int* pin = a; int* pout = c;
  for (int st = 1; st < 512; st <<= 1) {
    pout[tid]       = pin[tid]       + ((tid >= st)       ? pin[tid - st]       : 0);
    pout[tid + 256] = pin[tid + 256] + ((tid + 256 >= st) ? pin[tid + 256 - st] : 0);
    __syncthreads();
    int* t = pin; pin = pout; pout = t;
  }
  if (tid < NBKT)       { int ex = pin[tid] - v0;       bbase[tid] = ex;       gcur[tid] = ex; }
  if (tid + 256 < NBKT) { int ex = pin[tid + 256] - v1; bbase[tid + 256] = ex; gcur[tid + 256] = ex; }
  if (tid == 0) { bbase[NBKT] = E; rowptr[N] = E; }
}

// ---------------- pass A: scatter packed (src<<8 | dstlocal) grouped by coarse bucket ----
// One global atomic per (block,bucket) reserves a contiguous run; writes are
// dense runs -> full-line writebacks. Payload packed to 4B (src < 2^17).

__global__ __launch_bounds__(256) void k_bucket_scatter(const int* __restrict__ src, const int* __restrict__ dst,
                                                        int* __restrict__ gcur, unsigned* __restrict__ tmp,
                                                        int E, int NBKT) {
  __shared__ int hist[512], base[512];
  int tid = threadIdx.x;
  int ebeg = blockIdx.x * EPB;
  int eend = min(E, ebeg + EPB);
  for (int i = tid; i < NBKT; i += 256) hist[i] = 0;
  __syncthreads();
  for (int e = ebeg + tid; e < eend; e += 256) atomicAdd(&hist[dst[e] >> 8], 1);
  __syncthreads();
  for (int i = tid; i < NBKT; i += 256) {
    int c = hist[i];
    base[i] = c ? atomicAdd(&gcur[i], c) : 0;
    hist[i] = 0;
  }
  __syncthreads();
  for (int e = ebeg + tid; e < eend; e += 256) {
    int d = dst[e];
    int bkt = d >> 8;
    int o = base[bkt] + atomicAdd(&hist[bkt], 1);
    tmp[o] = ((unsigned)src[e] << 8) | (unsigned)(d & 255);
  }
}

// ---------------- pass B: per-bucket build: rowptr, dinv, csr (all LDS-local) ----------------

__global__ __launch_bounds__(256) void k_bucket_build(const unsigned* __restrict__ tmp, const int* __restrict__ bbase,
                                                      int* __restrict__ csr, int* __restrict__ rowptr,
                                                      float* __restrict__ dinv, int N) {
  int b = blockIdx.x;
  int tid = threadIdx.x;
  int node0 = b << 8;
  int nn = min(256, N - node0);
  int beg = bbase[b], end = bbase[b + 1], cnt = end - beg;
  __shared__ int h[256], off[256], cur[256];
  __shared__ int stage[MAXB];
  h[tid] = 0;
  __syncthreads();
  for (int e = beg + tid; e < end; e += 256) atomicAdd(&h[tmp[e] & 255], 1);
  __syncthreads();
  int deg = h[tid];
  off[tid] = deg;
  __syncthreads();
  for (int st = 1; st < 256; st <<= 1) {
    int t = (tid >= st) ? off[tid - st] : 0;
    __syncthreads();
    off[tid] += t;
    __syncthreads();
  }
  int excl = off[tid] - deg;
  cur[tid] = excl;
  if (tid < nn) {
    rowptr[node0 + tid] = beg + excl;
    dinv[node0 + tid] = rsqrtf((float)(deg + 1));  // +1 = self loop
  }
  __syncthreads();
  if (cnt <= MAXB) {
    for (int e = beg + tid; e < end; e += 256) {
      unsigned p = tmp[e];
      int pos = atomicAdd(&cur[p & 255], 1);
      stage[pos] = (int)(p >> 8);
    }
    __syncthreads();
    for (int k = tid; k < cnt; k += 256) csr[beg + k] = stage[k];
  } else {  // safety fallback (never taken for uniform-random dst)
    for (int e = beg + tid; e < end; e += 256) {
      unsigned p = tmp[e];
      int pos = atomicAdd(&cur[p & 255], 1);
      csr[beg + pos] = (int)(p >> 8);
    }
  }
}

// ---------------- GEMM + dinv prescale, bf16 output: g = bf16(dinv * (x @ W)) --------

template <int F_IN, int F_OUT, int TPN, int ROWS>
__global__ __launch_bounds__(256) void k_gemm(const float* __restrict__ x, const float* __restrict__ W,
                                              const float* __restrict__ dinv, unsigned short* __restrict__ g, int N) {
  constexpr int VPT = F_OUT / TPN;
  constexpr int GROUPS = 256 / TPN;
  constexpr int NB = GROUPS * ROWS;
  __shared__ float ws[F_IN * F_OUT];
  __shared__ float xs[NB][F_IN];
  int tid = threadIdx.x;
  int base = blockIdx.x * NB;
  for (int i = tid; i < F_IN * F_OUT; i += 256) ws[i] = W[i];
  for (int i = tid; i < NB * F_IN; i += 256) {
    int r = i / F_IN, c = i - r * F_IN;
    int node = base + r;
    xs[r][c ^ (r & 31)] = (node < N) ? x[(size_t)node * F_IN + c] : 0.f;
  }
  __syncthreads();
  int fg = tid % TPN, f0 = fg * VPT;
  int ng = tid / TPN;
  int r0 = ng * ROWS;
  float acc[ROWS][VPT];
#pragma unroll
  for (int r = 0; r < ROWS; ++r)
#pragma unroll
    for (int j = 0; j < VPT; ++j) acc[r][j] = 0.f;
  for (int k = 0; k < F_IN; ++k) {
    float wv[VPT];
#pragma unroll
    for (int j = 0; j < VPT; ++j) wv[j] = ws[k * F_OUT + f0 + j];
#pragma unroll
    for (int r = 0; r < ROWS; ++r) {
      float xv = xs[r0 + r][k ^ ((r0 + r) & 31)];
#pragma unroll
      for (int j = 0; j < VPT; ++j) acc[r][j] += xv * wv[j];
    }
  }
#pragma unroll
  for (int r = 0; r < ROWS; ++r) {
    int node = base + r0 + r;
    if (node < N) {
      float dv = dinv[node];
      if constexpr (VPT % 2 == 0) {
#pragma unroll
        for (int j = 0; j < VPT; j += 2) {
          unsigned u = (unsigned)f2b(dv * acc[r][j]) | ((unsigned)f2b(dv * acc[r][j + 1]) << 16);
          *(unsigned*)(&g[(size_t)node * F_OUT + f0 + j]) = u;
        }
      } else {
#pragma unroll
        for (int j = 0; j < VPT; ++j) g[(size_t)node * F_OUT + f0 + j] = f2b(dv * acc[r][j]);
      }
    }
  }
}

// ---------------- CSR aggregation (bf16 gather, f32 accumulate) ----------------

template <int F, bool RELU>
__global__ __launch_bounds__(256) void k_agg(const unsigned short* __restrict__ g, const int* __restrict__ rowptr,
                                             const int* __restrict__ csr, const float* __restrict__ dinv,
                                             const float* __restrict__ bias, float* __restrict__ out, int N) {
  int t = blockIdx.x * 256 + threadIdx.x;
  int grp = t / F;
  int f = t - grp * F;
  if (grp >= N) return;
  float acc = b2f(g[(size_t)grp * F + f]);  // self loop term
  int beg = rowptr[grp], end = rowptr[grp + 1];
  int j = beg;
  while (j < end && (j & 3)) { acc += b2f(g[(size_t)csr[j] * F + f]); ++j; }
  for (; j + 4 <= end; j += 4) {
    int4 ss = *(const int4*)(csr + j);
    float a0 = b2f(g[(size_t)ss.x * F + f]);
    float a1 = b2f(g[(size_t)ss.y * F + f]);
    float a2 = b2f(g[(size_t)ss.z * F + f]);
    float a3 = b2f(g[(size_t)ss.w * F + f]);
    acc += a0; acc += a1; acc += a2; acc += a3;
  }
  for (; j < end; ++j) acc += b2f(g[(size_t)csr[j] * F + f]);
  float v = dinv[grp] * acc + bias[f];
  if (RELU) v = fmaxf(v, 0.f);
  out[(size_t)grp * F + f] = v;
}

// ---------------- final layer aggregation (F=2, packed 4B rows) + log_softmax --------

__global__ __launch_bounds__(256) void k_final(const unsigned* __restrict__ g2, const int* __restrict__ rowptr,
                                               const int* __restrict__ csr, const float* __restrict__ dinv,
                                               const float* __restrict__ bias, float* __restrict__ out, int N) {
  int i = blockIdx.x * 256 + threadIdx.x;
  if (i >= N) return;
  unsigned s = g2[i];
  float a0 = b2f((unsigned short)s), a1 = b2f((unsigned short)(s >> 16));
  int beg = rowptr[i], end = rowptr[i + 1];
  for (int j = beg; j < end; ++j) {
    unsigned p = g2[csr[j]];
    a0 += b2f((unsigned short)p);
    a1 += b2f((unsigned short)(p >> 16));
  }
  float dv = dinv[i];
  float v0 = fmaf(dv, a0, bias[0]);
  float v1 = fmaf(dv, a1, bias[1]);
  float m = fmaxf(v0, v1);
  float lse = m + logf(expf(v0 - m) + expf(v1 - m));
  out[2 * (size_t)i] = v0 - lse;
  out[2 * (size_t)i + 1] = v1 - lse;
}

// ---------------- launch ----------------

extern "C" void kernel_launch(void* const* d_in, const int* in_sizes, int n_in,
                              void* d_out, int out_size, void* d_ws, size_t ws_size,
                              hipStream_t stream) {
  const float* x  = (const float*)d_in[0];
  const int*   ei = (const int*)d_in[1];
  const float* W1 = (const float*)d_in[2];
  const float* b1 = (const float*)d_in[3];
  const float* W2 = (const float*)d_in[4];
  const float* b2 = (const float*)d_in[5];
  const float* W3 = (const float*)d_in[6];
  const float* b3 = (const float*)d_in[7];
  float* out = (float*)d_out;

  int N = in_sizes[0] / 128;  // 100000
  int E = in_sizes[1] / 2;    // 3200000
  const int* src = ei;        // edge_index[0]
  const int* dst = ei + E;    // edge_index[1]
  int NBKT = (N + 255) >> 8;  // 391 coarse buckets of 256 nodes

  char* w = (char*)d_ws;
  size_t off = 0;
  auto carve = [&](size_t bytes) -> char* {
    char* p = w + off;
    off = (off + bytes + 255) & ~(size_t)255;
    return p;
  };
  float* dinv   = (float*)carve((size_t)N * 4);
  int*   rowptr = (int*)carve((size_t)(N + 1) * 4);
  int*   bhist  = (int*)carve(2048);
  int*   bbase  = (int*)carve(2048 + 4);
  int*   gcur   = (int*)carve(2048);
  int*   csr    = (int*)carve((size_t)E * 4);
  size_t gsz = (size_t)N * 64 * 2;             // bf16 g buffer
  if ((size_t)E * 4 > gsz) gsz = (size_t)E * 4;  // doubles as packed pair buffer
  unsigned short* gbuf = (unsigned short*)carve(gsz);
  float* hbuf   = (float*)carve((size_t)N * 64 * 4);
  unsigned* tmp = (unsigned*)gbuf;  // pair buffer dead once k_bucket_build finishes
  (void)ws_size; (void)n_in; (void)out_size;

  int nbA = (E + EPB - 1) / EPB;  // 391

  hipMemsetAsync(bhist, 0, (size_t)NBKT * 4, stream);
  k_bhist<<<nbA, 256, 0, stream>>>(dst, bhist, E, NBKT);
  k_bscan<<<1, 256, 0, stream>>>(bhist, bbase, gcur, rowptr, E, N, NBKT);
  k_bucket_scatter<<<nbA, 256, 0, stream>>>(src, dst, gcur, tmp, E, NBKT);
  k_bucket_build<<<NBKT, 256, 0, stream>>>(tmp, bbase, csr, rowptr, dinv, N);

  // layer 1: 128 -> 64, relu
  k_gemm<128, 64, 16, 4><<<(N + 63) / 64, 256, 0, stream>>>(x, W1, dinv, gbuf, N);
  k_agg<64, true><<<(unsigned)(((long long)N * 64 + 255) / 256), 256, 0, stream>>>(gbuf, rowptr, csr, dinv, b1, hbuf, N);
  // layer 2: 64 -> 32, relu
  k_gemm<64, 32, 8, 4><<<(N + 127) / 128, 256, 0, stream>>>(hbuf, W2, dinv, gbuf, N);
  k_agg<32, true><<<(unsigned)(((long long)N * 32 + 255) / 256), 256, 0, stream>>>(gbuf, rowptr, csr, dinv, b2, hbuf, N);
  // layer 3: 32 -> 2, log_softmax
  k_gemm<32, 2, 1, 1><<<(N + 255) / 256, 256, 0, stream>>>(hbuf, W3, dinv, gbuf, N);
  k_final<<<(unsigned)((N + 255) / 256), 256, 0, stream>>>((const unsigned*)gbuf, rowptr, csr, dinv, b3, out, N);
}